// Round 5
// baseline (176.763 us; speedup 1.0000x reference)
//
#include <hip/hip_runtime.h>
#include <cstdint>

typedef unsigned short u16;
typedef __attribute__((ext_vector_type(8))) short bf16x8;
typedef __attribute__((ext_vector_type(4))) float f32x4;

#define B_   128
#define P_   2048
#define NC_  10
#define F_   160      // NC*CLO
#define NBLK 512      // k_pass blocks: 2 per CU
#define PPB  4        // p-tiles per block
#define NTHR 512

__device__ __forceinline__ u16 f2bf(float f) {
    union { float f; unsigned u; } v; v.f = f;
    unsigned r = v.u + 0x7FFFu + ((v.u >> 16) & 1u);   // RNE
    return (u16)(r >> 16);
}
__device__ __forceinline__ float bf2f(u16 h) {
    union { unsigned u; float f; } v; v.u = ((unsigned)h) << 16;
    return v.f;
}

// async global->LDS, 16B per lane; LDS dest = wave-uniform base + lane*16 (m97/m104).
__device__ __forceinline__ void gl_lds16(const void* g, void* l) {
    typedef __attribute__((address_space(3))) unsigned lds_uint;
    typedef __attribute__((address_space(1))) const unsigned glob_uint;
    __builtin_amdgcn_global_load_lds((glob_uint*)(uintptr_t)g,
                                     (lds_uint*)(unsigned)(uintptr_t)l, 16, 0, 0);
}

// Fused prep. Blocks 0..4095: squash x along NP=32, bf16, write xb[p] in DMA-deposit
// order with 16B-chunk swizzle (row b: chunk q at b*64B + ((q+(b>>1))&3)*16B).
// Blocks 4096..6143: w[p][k][f] fp32 -> wb[p] bf16 transposed, same swizzle on rows f.
__global__ void k_prep(const float* __restrict__ t, const float* __restrict__ w,
                       u16* __restrict__ xb, u16* __restrict__ wb) {
    const int blk = blockIdx.x, tid = threadIdx.x;
    if (blk < 4096) {
        int g = blk * 256 + tid;
        int pair = g >> 2, sub = g & 3;          // sub = q chunk
        int p = pair & 2047, b = pair >> 11;
        const float4* tg = (const float4*)t;
        int fi = pair * 8 + sub * 2;
        float4 va = tg[fi], vb = tg[fi + 1];
        float ss = va.x*va.x + va.y*va.y + va.z*va.z + va.w*va.w
                 + vb.x*vb.x + vb.y*vb.y + vb.z*vb.z + vb.w*vb.w;
        ss += __shfl_xor(ss, 1);      // quad holds full 32-elem sum
        ss += __shfl_xor(ss, 2);
        float fct = ss / ((1.f + ss) * sqrtf(ss));
        u16 h[8] __attribute__((aligned(16)));
        h[0]=f2bf(va.x*fct); h[1]=f2bf(va.y*fct); h[2]=f2bf(va.z*fct); h[3]=f2bf(va.w*fct);
        h[4]=f2bf(vb.x*fct); h[5]=f2bf(vb.y*fct); h[6]=f2bf(vb.z*fct); h[7]=f2bf(vb.w*fct);
        int off = (sub + (b >> 1)) & 3;
        *(uint4*)(xb + p * 4096 + b * 32 + off * 8) = *(const uint4*)h;
    } else {
        __shared__ u16 wl[32 * F_];
        int p = blk - 4096;
        const float4* wp = (const float4*)(w + p * 32 * F_);
        for (int e4 = tid; e4 < 1280; e4 += 256) {
            float4 v = wp[e4];
            u16 h[4] __attribute__((aligned(8)));
            h[0]=f2bf(v.x); h[1]=f2bf(v.y); h[2]=f2bf(v.z); h[3]=f2bf(v.w);
            *(ushort4*)(wl + e4 * 4) = *(const ushort4*)h;
        }
        __syncthreads();
        u16* wo = wb + p * 5120;
        for (int sid = tid; sid < 640; sid += 256) {
            int f = sid >> 2, k0 = (sid & 3) << 3, q = sid & 3;
            u16 tmp[8] __attribute__((aligned(16)));
#pragma unroll
            for (int j = 0; j < 8; ++j) tmp[j] = wl[(k0 + j) * F_ + f];
            int off = (q + (f >> 1)) & 3;
            *(uint4*)(wo + f * 32 + off * 8) = *(const uint4*)tmp;
        }
    }
}

// One routing pass, async double-buffered LDS staging via global_load_lds.
// MODE 0: c=0.1 uniform (MFMA-chained). MODE>=1: t = u.vprev (bias folded
// algebraically: vprev = v0 for pass 1, v0+v1 for pass 2), softmax, weighted sum.
template<int MODE>
__global__ __launch_bounds__(NTHR, 2) void k_pass(
        const u16* __restrict__ xb, const u16* __restrict__ wb,
        const float* __restrict__ vprev, u16* __restrict__ s_part)
{
    __shared__ __align__(16) u16 xt[2][4096];   // 2 x 8192 B
    __shared__ __align__(16) u16 wt[2][5120];   // 2 x 10240 B
    const int tid = threadIdx.x, blk = blockIdx.x;
    const int L = tid & 63, wv = tid >> 6;
    const int q = L >> 4, col = L & 15;
    const int b = wv * 16 + col;
    const int p0 = blk * PPB;
    const int off8 = ((q + (col >> 1)) & 3) * 8;   // swizzled 16B-chunk selector

    float4 vv[NC_];
    if (MODE != 0) {
#pragma unroll
        for (int n = 0; n < NC_; ++n)
            vv[n] = *(const float4*)(vprev + b * F_ + n * 16 + q * 4);
    }

    f32x4 s_acc[NC_];
#pragma unroll
    for (int n = 0; n < NC_; ++n) s_acc[n] = (f32x4){0.f, 0.f, 0.f, 0.f};

    auto issue = [&](int p, int c) {
        const u16* xg = xb + p * 4096 + wv * 512 + L * 8;   // lane: 16B, wave: 1KB chunk
        const u16* wg = wb + p * 5120 + wv * 512 + L * 8;
        gl_lds16(xg, &xt[c][wv * 512]);
        gl_lds16(wg, &wt[c][wv * 512]);
        if (wv < 2)   // wave-uniform: waves 0,1 carry w chunks 8,9
            gl_lds16(wb + p * 5120 + (8 + wv) * 512 + L * 8, &wt[c][(8 + wv) * 512]);
    };

    issue(p0, 0);
#pragma unroll
    for (int pp = 0; pp < PPB; ++pp) {
        __builtin_amdgcn_s_waitcnt(0x0f70);   // vmcnt(0): tile pp's DMA landed
        __syncthreads();                      // all waves: tile pp visible, prev buf free
        if (pp + 1 < PPB) issue(p0 + pp + 1, (pp + 1) & 1);   // flies during compute
        const u16* xc = xt[pp & 1];
        const u16* wc = wt[pp & 1];

        bf16x8 bfrag = *(const bf16x8*)&xc[b * 32 + off8];   // x[b][k=q*8+j]
        if (MODE == 0) {
#pragma unroll
            for (int n = 0; n < NC_; ++n) {
                bf16x8 afrag = *(const bf16x8*)&wc[(n * 16 + col) * 32 + off8];
                s_acc[n] = __builtin_amdgcn_mfma_f32_16x16x32_bf16(afrag, bfrag, s_acc[n], 0, 0, 0);
            }
        } else {
            float tt[NC_];
#pragma unroll
            for (int n = 0; n < NC_; ++n) {
                bf16x8 afrag = *(const bf16x8*)&wc[(n * 16 + col) * 32 + off8];
                f32x4 z = {0.f, 0.f, 0.f, 0.f};
                f32x4 acc = __builtin_amdgcn_mfma_f32_16x16x32_bf16(afrag, bfrag, z, 0, 0, 0);
                float t = acc[0]*vv[n].x + acc[1]*vv[n].y + acc[2]*vv[n].z + acc[3]*vv[n].w;
                t += __shfl_xor(t, 16);   // full 16-elem dot over k'
                t += __shfl_xor(t, 32);
                tt[n] = t;
            }
            float mx = tt[0];
#pragma unroll
            for (int n = 1; n < NC_; ++n) mx = fmaxf(mx, tt[n]);
            float den = 0.f;
#pragma unroll
            for (int n = 0; n < NC_; ++n) { tt[n] = __expf(tt[n] - mx); den += tt[n]; }
            float inv = 1.f / den;
#pragma unroll
            for (int n = 0; n < NC_; ++n) {   // recompute acc: keeps live regs < 128
                bf16x8 afrag = *(const bf16x8*)&wc[(n * 16 + col) * 32 + off8];
                f32x4 z = {0.f, 0.f, 0.f, 0.f};
                f32x4 acc = __builtin_amdgcn_mfma_f32_16x16x32_bf16(afrag, bfrag, z, 0, 0, 0);
                float cf = tt[n] * inv;
#pragma unroll
                for (int r = 0; r < 4; ++r) s_acc[n][r] += cf * acc[r];
            }
        }
    }

    u16* sp = s_part + blk * (B_ * F_);
    const float sc = (MODE == 0) ? 0.1f : 1.f;
#pragma unroll
    for (int n = 0; n < NC_; ++n) {
        u16 h[4] __attribute__((aligned(8)));
#pragma unroll
        for (int r = 0; r < 4; ++r) h[r] = f2bf(s_acc[n][r] * sc);
        *(ushort4*)(sp + b * F_ + n * 16 + q * 4) = *(const ushort4*)h;
    }
}

// Sum bf16 partials over NBLK groups, squash along CLO=16.
// ADD: write squash(s) + vprev (produces v0+v1 for the next pass's logits).
template<int ADD>
__global__ void k_red(const u16* __restrict__ s_part,
                      const float* __restrict__ vprev, float* __restrict__ vout) {
    __shared__ float r0s[256], r1s[256];
    const int tid = threadIdx.x, blk = blockIdx.x;
    const int pid = tid & 31, part = tid >> 5;
    const uint* sp = (const uint*)s_part;
    const int opair = blk * 32 + pid;           // 10240 pairs total
    float a0 = 0.f, a1 = 0.f;
#pragma unroll 8
    for (int g = part; g < NBLK; g += 8) {
        uint u = sp[g * 10240 + opair];
        a0 += bf2f((u16)(u & 0xffff));
        a1 += bf2f((u16)(u >> 16));
    }
    r0s[tid] = a0; r1s[tid] = a1;
    __syncthreads();
    if (tid < 32) {
        float s0 = 0.f, s1 = 0.f;
#pragma unroll
        for (int k = 0; k < 8; ++k) { s0 += r0s[k * 32 + tid]; s1 += r1s[k * 32 + tid]; }
        float sq = s0 * s0 + s1 * s1;
        sq += __shfl_xor(sq, 1);    // 8 lanes = 16 elems of one (b,n)
        sq += __shfl_xor(sq, 2);
        sq += __shfl_xor(sq, 4);
        float fct = sq / ((1.f + sq) * sqrtf(sq));
        float2 o = make_float2(s0 * fct, s1 * fct);
        if (ADD) {
            float2 pv = *(const float2*)(vprev + 2 * (blk * 32 + tid));
            o.x += pv.x; o.y += pv.y;
        }
        *(float2*)(vout + 2 * (blk * 32 + tid)) = o;
    }
}

extern "C" void kernel_launch(void* const* d_in, const int* in_sizes, int n_in,
                              void* d_out, int out_size, void* d_ws, size_t ws_size,
                              hipStream_t stream) {
    const float* tensor = (const float*)d_in[0];
    const float* weight = (const float*)d_in[1];
    float* out = (float*)d_out;
    char* ws = (char*)d_ws;

    u16*   xb     = (u16*)(ws);                       // 16,777,216 B
    u16*   wb     = (u16*)(ws + 16777216);            // 20,971,520 B
    u16*   s_part = (u16*)(ws + 37748736);            // 512*20480*2 = 20,971,520 B
    float* v0     = (float*)(ws + 58720256);          // 81,920 B
    float* vs     = (float*)(ws + 58802176);          // 81,920 B (v0 + v1)

    k_prep<<<6144, 256, 0, stream>>>(tensor, weight, xb, wb);

    k_pass<0><<<NBLK, NTHR, 0, stream>>>(xb, wb, nullptr, s_part);
    k_red<0><<<320, 256, 0, stream>>>(s_part, nullptr, v0);
    k_pass<1><<<NBLK, NTHR, 0, stream>>>(xb, wb, v0, s_part);
    k_red<1><<<320, 256, 0, stream>>>(s_part, v0, vs);
    k_pass<2><<<NBLK, NTHR, 0, stream>>>(xb, wb, vs, s_part);
    k_red<0><<<320, 256, 0, stream>>>(s_part, nullptr, out);
}